// Round 7
// baseline (184.558 us; speedup 1.0000x reference)
//
#include <hip/hip_runtime.h>
#include <hip/hip_bf16.h>
#include <math.h>

namespace {
constexpr int B_ = 16, C_ = 256, L_ = 1024, NH_ = 8, DH_ = 32;

typedef __attribute__((ext_vector_type(8))) short short8v;   // 8 bf16
typedef __attribute__((ext_vector_type(4))) float float4v;   // 4 fp32

// fp32 -> bf16 RNE
__device__ __forceinline__ short f2bf(float f) {
    unsigned u = __builtin_bit_cast(unsigned, f);
    u += 0x7fffu + ((u >> 16) & 1u);
    return (short)(u >> 16);
}
__device__ __forceinline__ float bf2f(short s) {
    unsigned u = ((unsigned)(unsigned short)s) << 16;
    return __builtin_bit_cast(float, u);
}
// packed fp32x2 -> bf16x2 (v_cvt_pk_bf16_f32 on gfx950), a in low half
__device__ __forceinline__ unsigned pkrn(float a, float b) {
    float2 f; f.x = a; f.y = b;
    __hip_bfloat162 h = __float22bfloat162_rn(f);
    unsigned u;
    __builtin_memcpy(&u, &h, sizeof(u));
    return u;
}
// async global->LDS, 16B per lane; LDS dest must be lane-contiguous
__device__ __forceinline__ void gld16(const short* g, short* l) {
    __builtin_amdgcn_global_load_lds(
        (const __attribute__((address_space(1))) unsigned*)g,
        (__attribute__((address_space(3))) unsigned*)l, 16, 0, 0);
}

// ---------------------------------------------------------------------------
// x [b][c][l] fp32  ->  Xt hi/lo bf16 [b][l][c]   (64x64 LDS transpose tiles)
// ---------------------------------------------------------------------------
__global__ __launch_bounds__(256) void xpose_kernel(
    const float* __restrict__ x, short* __restrict__ xthi, short* __restrict__ xtlo)
{
    const int lt = blockIdx.x, ct = blockIdx.y, b = blockIdx.z;
    const int t = threadIdx.x;
    __shared__ float sX[64][68];

#pragma unroll
    for (int e = 0; e < 4; ++e) {
        const int row = e * 16 + (t >> 4);          // local c
        const int col = (t & 15) * 4;               // local l
        float4 v = *(const float4*)&x[((size_t)b * C_ + ct * 64 + row) * L_ + lt * 64 + col];
        *(float4*)&sX[row][col] = v;
    }
    __syncthreads();

    const int l = t & 63, cg = t >> 6;              // 16 channels per thread
    short hi[16], lo[16];
#pragma unroll
    for (int i = 0; i < 16; ++i) {
        const float v = sX[cg * 16 + i][l];
        hi[i] = f2bf(v);
        lo[i] = f2bf(v - bf2f(hi[i]));
    }
    const size_t base = ((size_t)b * L_ + lt * 64 + l) * C_ + ct * 64 + cg * 16;
    *(short8v*)&xthi[base]     = *(short8v*)&hi[0];
    *(short8v*)&xthi[base + 8] = *(short8v*)&hi[8];
    *(short8v*)&xtlo[base]     = *(short8v*)&lo[0];
    *(short8v*)&xtlo[base + 8] = *(short8v*)&lo[8];
}

// ---------------------------------------------------------------------------
// Stack weights:
//   WA  [768][768]: rows = {q,k,v} channels; k-phases = [Whi | Wlo | Whi]
//   WoA [256][512]: k-phases = [Wohi | Wolo]
// ---------------------------------------------------------------------------
__global__ __launch_bounds__(256) void stackw_kernel(
    const float* __restrict__ wq, const float* __restrict__ wk,
    const float* __restrict__ wv, const float* __restrict__ wo,
    short* __restrict__ WA, short* __restrict__ WoA)
{
    const int g = blockIdx.x * 256 + threadIdx.x;
    if (g < 768 * 256) {
        const int o = g >> 8, cc = g & 255;
        const float* src = (o < 256) ? wq : (o < 512) ? wk : wv;
        const float v = src[(size_t)(o & 255) * 256 + cc];
        const short hi = f2bf(v);
        const short lo = f2bf(v - bf2f(hi));
        WA[(size_t)o * 768 + cc]       = hi;
        WA[(size_t)o * 768 + 256 + cc] = lo;
        WA[(size_t)o * 768 + 512 + cc] = hi;
    } else {
        const int g2 = g - 768 * 256;
        const int o = g2 >> 8, cc = g2 & 255;
        const float v = wo[(size_t)o * 256 + cc];
        const short hi = f2bf(v);
        const short lo = f2bf(v - bf2f(hi));
        WoA[(size_t)o * 512 + cc]       = hi;
        WoA[(size_t)o * 512 + 256 + cc] = lo;
    }
}

// ---------------------------------------------------------------------------
// MFMA GEMM (m97 structure): D[M-tile 128][L-tile 128] = A[M][K] * B(t)[l][k]
// ---------------------------------------------------------------------------
template <int KTOT, int EPI>
__global__ __launch_bounds__(256, 2) void gemm_kernel(
    const short* __restrict__ A, const short* __restrict__ B0, const short* __restrict__ B1,
    const float* __restrict__ bias0, const float* __restrict__ bias1, const float* __restrict__ bias2,
    float qscale, void* __restrict__ out0, void* __restrict__ out1, void* __restrict__ out2)
{
    const int lt = blockIdx.x, ot = blockIdx.y, b = blockIdx.z;
    const int t = threadIdx.x, wv = t >> 6, lane = t & 63;
    const int quad = lane >> 4, c = lane & 15;
    const int wo = (wv & 1) * 64, wl = (wv >> 1) * 64;

    __shared__ short sA[128 * 32];   // [row][k], 64B rows, glds-contiguous
    __shared__ short sB[128 * 32];

    float4v acc[4][4];
#pragma unroll
    for (int i = 0; i < 4; ++i)
#pragma unroll
        for (int j = 0; j < 4; ++j) acc[i][j] = (float4v)0.f;

    const short* Arow = A + (size_t)(ot * 128) * KTOT;
    const int srow = t >> 2, sseg = t & 3;          // staging: 4 lanes x 16B per row

    for (int kk = 0; kk < KTOT / 32; ++kk) {
        const int phase = kk >> 3;
        const short* Bt = (phase < 2) ? B0 : B1;
        const int koff = (kk & 7) * 32;
        __syncthreads();
#pragma unroll
        for (int e = 0; e < 2; ++e) {
            gld16(Arow + (size_t)(e * 64 + srow) * KTOT + kk * 32 + sseg * 8,
                  &sA[(e * 256 + t) * 8]);
            gld16(Bt + ((size_t)b * L_ + lt * 128 + e * 64 + srow) * 256 + koff + sseg * 8,
                  &sB[(e * 256 + t) * 8]);
        }
        __syncthreads();

        short8v af[4], bf[4];
#pragma unroll
        for (int i = 0; i < 4; ++i) af[i] = *(const short8v*)&sA[(wo + 16 * i + c) * 32 + quad * 8];
#pragma unroll
        for (int j = 0; j < 4; ++j) bf[j] = *(const short8v*)&sB[(wl + 16 * j + c) * 32 + quad * 8];
#pragma unroll
        for (int i = 0; i < 4; ++i)
#pragma unroll
            for (int j = 0; j < 4; ++j)
                acc[i][j] = __builtin_amdgcn_mfma_f32_16x16x32_bf16(af[i], bf[j], acc[i][j], 0, 0, 0);
    }

    if constexpr (EPI == 0) {
        const int typ = ot >> 1;                     // 0=q 1=k 2=v
        const int chbase = (ot & 1) * 128 + wo;
        const float* bp = (typ == 0) ? bias0 : (typ == 1) ? bias1 : bias2;
        const float sc = (typ == 0) ? qscale : 1.f;
        short* outp = (short*)((typ == 0) ? out0 : (typ == 1) ? out1 : out2);
        if (typ < 2) {
            // q/k -> [b][h][l][d] bf16, short4 packed over r (consecutive d)
#pragma unroll
            for (int i = 0; i < 4; ++i) {
                const int ch0 = chbase + 16 * i + quad * 4;
                const int head = ch0 >> 5, d0 = ch0 & 31;
                float bias[4];
#pragma unroll
                for (int r = 0; r < 4; ++r) bias[r] = bp[ch0 + r];
#pragma unroll
                for (int j = 0; j < 4; ++j) {
                    const int l = lt * 128 + wl + 16 * j + c;
                    short4 sv;
                    sv.x = f2bf((acc[i][j][0] + bias[0]) * sc);
                    sv.y = f2bf((acc[i][j][1] + bias[1]) * sc);
                    sv.z = f2bf((acc[i][j][2] + bias[2]) * sc);
                    sv.w = f2bf((acc[i][j][3] + bias[3]) * sc);
                    *(short4*)&outp[(((size_t)b * NH_ + head) * L_ + l) * 32 + d0] = sv;
                }
            }
        } else {
            // v -> [b][c][l] bf16
#pragma unroll
            for (int i = 0; i < 4; ++i)
#pragma unroll
                for (int r = 0; r < 4; ++r) {
                    const int ch = chbase + 16 * i + quad * 4 + r;
                    const float bias = bp[ch];
#pragma unroll
                    for (int j = 0; j < 4; ++j)
                        outp[((size_t)b * C_ + ch) * L_ + lt * 128 + wl + 16 * j + c] =
                            f2bf(acc[i][j][r] + bias);
                }
        }
    } else {
        float* outp = (float*)out0;
#pragma unroll
        for (int i = 0; i < 4; ++i)
#pragma unroll
            for (int r = 0; r < 4; ++r) {
                const int ch = ot * 128 + wo + 16 * i + quad * 4 + r;
                const float bias = bias0[ch];
#pragma unroll
                for (int j = 0; j < 4; ++j)
                    outp[((size_t)b * C_ + ch) * L_ + lt * 128 + wl + 16 * j + c] =
                        acc[i][j][r] + bias;
            }
    }
}

// ---------------------------------------------------------------------------
// MFMA flash attention, S^T form, XCD-swizzled, 32 q/wave, 2-tile software
// pipeline. Register sets A/B alternate; K and V for a tile are issued a
// full half-body (~400 cyc) before use — no copy, no vmcnt-drain convoy.
// Softmax denominator: 4 independent partial accumulators per q-frag
// (breaks the 16-deep serial fp-add chain; no-fast-math can't reassociate).
// ---------------------------------------------------------------------------
__global__ __launch_bounds__(256, 4) void attn_kernel(
    const short* __restrict__ qt,   // [b][h][l][d] bf16 (scale*log2e folded)
    const short* __restrict__ kt,   // [b][h][l][d] bf16
    const short* __restrict__ vb,   // [b][c][l]    bf16
    short* __restrict__ athi)       // [b][l][c]    bf16
{
    const int flat = blockIdx.x;
    const int g = ((flat >> 6) << 3) | (flat & 7);  // (b,h) group
    const int chunk = (flat >> 3) & 7;
    const int b = g >> 3, h = g & 7;
    const int t = threadIdx.x;
    const int wv = t >> 6, lane = t & 63;
    const int quad = lane >> 4, c = lane & 15;
    const int lq0 = chunk * 128 + wv * 32;          // wave's 32 queries

    // per-wave, per-qf P^T: [lq 16][key 64 + pad], stride 72 shorts = 144 B
    // rows are 16B-multiples; read banks 4c+const -> <=2-way (free)
    __shared__ __align__(16) short sPT[4][2][16][72];

    const size_t bh = (size_t)b * NH_ + h;
    const short* qbase = qt + (bh * L_) * 32;
    const short* kbase = kt + (bh * L_) * 32;
    const size_t vrow = (size_t)b * C_ + h * DH_;

    short8v qfrag[2];
#pragma unroll
    for (int qf = 0; qf < 2; ++qf)
        qfrag[qf] = *(const short8v*)(qbase + (size_t)(lq0 + qf * 16 + c) * 32 + quad * 8);

    float lp4[2][4];
#pragma unroll
    for (int qf = 0; qf < 2; ++qf)
#pragma unroll
        for (int r = 0; r < 4; ++r) lp4[qf][r] = 0.f;
    float4v o_acc[2][2];
#pragma unroll
    for (int qf = 0; qf < 2; ++qf) { o_acc[qf][0] = (float4v)0.f; o_acc[qf][1] = (float4v)0.f; }

    auto load_tile = [&](int m0, short8v (&kf)[4], short8v (&vf)[2][2]) {
#pragma unroll
        for (int kb = 0; kb < 4; ++kb)
            kf[kb] = *(const short8v*)(kbase + (size_t)(m0 + kb * 16 + c) * 32 + quad * 8);
#pragma unroll
        for (int kc = 0; kc < 2; ++kc)
#pragma unroll
            for (int nb2 = 0; nb2 < 2; ++nb2)
                vf[kc][nb2] = *(const short8v*)(vb + (vrow + nb2 * 16 + c) * L_ + m0 + kc * 32 + quad * 8);
    };

    auto process = [&](const short8v (&kf)[4], const short8v (&vf)[2][2]) {
        float4v st[2][4];
#pragma unroll
        for (int qf = 0; qf < 2; ++qf)
#pragma unroll
            for (int kb = 0; kb < 4; ++kb)
                st[qf][kb] = __builtin_amdgcn_mfma_f32_16x16x32_bf16(kf[kb], qfrag[qf], (float4v)0.f, 0, 0, 0);
#pragma unroll
        for (int qf = 0; qf < 2; ++qf)
#pragma unroll
            for (int kb = 0; kb < 4; ++kb) {
                float p[4];
#pragma unroll
                for (int r = 0; r < 4; ++r) {
                    p[r] = __builtin_amdgcn_exp2f(st[qf][kb][r]);
                    lp4[qf][r] += p[r];          // 4 independent chains per qf
                }
                uint2 w;
                w.x = pkrn(p[0], p[1]);
                w.y = pkrn(p[2], p[3]);
                *(uint2*)&sPT[wv][qf][c][kb * 16 + quad * 4] = w;
            }
#pragma unroll
        for (int qf = 0; qf < 2; ++qf)
#pragma unroll
            for (int kc = 0; kc < 2; ++kc) {
                const short8v pf = *(const short8v*)&sPT[wv][qf][c][kc * 32 + quad * 8];
#pragma unroll
                for (int nb2 = 0; nb2 < 2; ++nb2)
                    o_acc[qf][nb2] = __builtin_amdgcn_mfma_f32_16x16x32_bf16(vf[kc][nb2], pf, o_acc[qf][nb2], 0, 0, 0);
            }
    };

    short8v kfA[4], vfA[2][2], kfB[4], vfB[2][2];
    load_tile(0, kfA, vfA);

    for (int i = 0; i < 8; ++i) {                  // 2 tiles per body
        const int m1 = i * 128 + 64;               // tile 2i+1 (never wraps)
        const int m2 = (i * 128 + 128) & (L_ - 1); // tile 2i+2 (wraps on last)
        load_tile(m1, kfB, vfB);
        process(kfA, vfA);
        load_tile(m2, kfA, vfA);
        process(kfB, vfB);
    }

#pragma unroll
    for (int qf = 0; qf < 2; ++qf) {
        float l = (lp4[qf][0] + lp4[qf][1]) + (lp4[qf][2] + lp4[qf][3]);
        l += __shfl_xor(l, 16);
        l += __shfl_xor(l, 32);
        const float inv = 1.f / l;
        // At[b][l][c]: l = lq0 + qf*16 + c, ch = h*32 + nb2*16 + quad*4 + r
#pragma unroll
        for (int nb2 = 0; nb2 < 2; ++nb2) {
            short4 sv;
            sv.x = f2bf(o_acc[qf][nb2][0] * inv);
            sv.y = f2bf(o_acc[qf][nb2][1] * inv);
            sv.z = f2bf(o_acc[qf][nb2][2] * inv);
            sv.w = f2bf(o_acc[qf][nb2][3] * inv);
            *(short4*)&athi[((size_t)b * L_ + lq0 + qf * 16 + c) * C_ + h * DH_ + nb2 * 16 + quad * 4] = sv;
        }
    }
}

}  // namespace

extern "C" void kernel_launch(void* const* d_in, const int* in_sizes, int n_in,
                              void* d_out, int out_size, void* d_ws, size_t ws_size,
                              hipStream_t stream) {
    const float* x   = (const float*)d_in[0];
    const float* w_q = (const float*)d_in[1];
    const float* b_q = (const float*)d_in[2];
    const float* w_k = (const float*)d_in[3];
    const float* b_k = (const float*)d_in[4];
    const float* w_v = (const float*)d_in[5];
    const float* b_v = (const float*)d_in[6];
    const float* w_o = (const float*)d_in[7];
    const float* b_o = (const float*)d_in[8];
    float* out = (float*)d_out;

    // workspace (shorts): Xthi | Xtlo | WA | WoA | qt | kt | vb | Athi  ~52 MB
    const size_t NT = (size_t)B_ * L_ * C_;   // 4,194,304
    short* xthi = (short*)d_ws;
    short* xtlo = xthi + NT;
    short* WA   = xtlo + NT;                  // 768*768
    short* WoA  = WA + 768 * 768;             // 256*512
    short* qt   = WoA + 256 * 512;
    short* kt   = qt + NT;
    short* vb   = kt + NT;
    short* athi = vb + NT;

    const float scale_q = 0.17677669529663687f * 1.4426950408889634f; // 1/sqrt(32)*log2(e)

    xpose_kernel<<<dim3(L_ / 64, C_ / 64, B_), 256, 0, stream>>>(x, xthi, xtlo);
    stackw_kernel<<<dim3(1024), 256, 0, stream>>>(w_q, w_k, w_v, w_o, WA, WoA);
    gemm_kernel<768, 0><<<dim3(L_ / 128, 6, B_), 256, 0, stream>>>(
        WA, xthi, xtlo, b_q, b_k, b_v, scale_q, qt, kt, vb);
    attn_kernel<<<dim3(1024), 256, 0, stream>>>(qt, kt, vb, athi);
    gemm_kernel<512, 1><<<dim3(L_ / 128, 2, B_), 256, 0, stream>>>(
        WoA, athi, athi, b_o, nullptr, nullptr, 1.f, out, nullptr, nullptr);
}

// Round 8
// 154.779 us; speedup vs baseline: 1.1924x; 1.1924x over previous
//
#include <hip/hip_runtime.h>
#include <hip/hip_bf16.h>
#include <math.h>

namespace {
constexpr int B_ = 16, C_ = 256, L_ = 1024, NH_ = 8, DH_ = 32;

typedef __attribute__((ext_vector_type(8))) short short8v;   // 8 bf16
typedef __attribute__((ext_vector_type(4))) float float4v;   // 4 fp32

// fp32 -> bf16 RNE
__device__ __forceinline__ short f2bf(float f) {
    unsigned u = __builtin_bit_cast(unsigned, f);
    u += 0x7fffu + ((u >> 16) & 1u);
    return (short)(u >> 16);
}
__device__ __forceinline__ float bf2f(short s) {
    unsigned u = ((unsigned)(unsigned short)s) << 16;
    return __builtin_bit_cast(float, u);
}
// packed fp32x2 -> bf16x2 (v_cvt_pk_bf16_f32 on gfx950), a in low half
__device__ __forceinline__ unsigned pkrn(float a, float b) {
    float2 f; f.x = a; f.y = b;
    __hip_bfloat162 h = __float22bfloat162_rn(f);
    unsigned u;
    __builtin_memcpy(&u, &h, sizeof(u));
    return u;
}
// async global->LDS, 16B per lane; LDS dest must be lane-contiguous
__device__ __forceinline__ void gld16(const short* g, short* l) {
    __builtin_amdgcn_global_load_lds(
        (const __attribute__((address_space(1))) unsigned*)g,
        (__attribute__((address_space(3))) unsigned*)l, 16, 0, 0);
}

// ---------------------------------------------------------------------------
// x [b][c][l] fp32  ->  Xt hi bf16 [b][l][c]   (64x64 LDS transpose tiles)
// (Xlo dropped: bf16 rounding of q/k/v dominates the error budget anyway)
// ---------------------------------------------------------------------------
__global__ __launch_bounds__(256) void xpose_kernel(
    const float* __restrict__ x, short* __restrict__ xthi)
{
    const int lt = blockIdx.x, ct = blockIdx.y, b = blockIdx.z;
    const int t = threadIdx.x;
    __shared__ float sX[64][68];

#pragma unroll
    for (int e = 0; e < 4; ++e) {
        const int row = e * 16 + (t >> 4);          // local c
        const int col = (t & 15) * 4;               // local l
        float4 v = *(const float4*)&x[((size_t)b * C_ + ct * 64 + row) * L_ + lt * 64 + col];
        *(float4*)&sX[row][col] = v;
    }
    __syncthreads();

    const int l = t & 63, cg = t >> 6;              // 16 channels per thread
    short hi[16];
#pragma unroll
    for (int i = 0; i < 16; ++i) hi[i] = f2bf(sX[cg * 16 + i][l]);
    const size_t base = ((size_t)b * L_ + lt * 64 + l) * C_ + ct * 64 + cg * 16;
    *(short8v*)&xthi[base]     = *(short8v*)&hi[0];
    *(short8v*)&xthi[base + 8] = *(short8v*)&hi[8];
}

// ---------------------------------------------------------------------------
// Stack weights:
//   WA  [768][512]: rows = {q,k,v} channels; k-phases = [Whi | Wlo]
//   WoA [256][512]: k-phases = [Wohi | Wolo]
// ---------------------------------------------------------------------------
__global__ __launch_bounds__(256) void stackw_kernel(
    const float* __restrict__ wq, const float* __restrict__ wk,
    const float* __restrict__ wv, const float* __restrict__ wo,
    short* __restrict__ WA, short* __restrict__ WoA)
{
    const int g = blockIdx.x * 256 + threadIdx.x;
    if (g < 768 * 256) {
        const int o = g >> 8, cc = g & 255;
        const float* src = (o < 256) ? wq : (o < 512) ? wk : wv;
        const float v = src[(size_t)(o & 255) * 256 + cc];
        const short hi = f2bf(v);
        const short lo = f2bf(v - bf2f(hi));
        WA[(size_t)o * 512 + cc]       = hi;
        WA[(size_t)o * 512 + 256 + cc] = lo;
    } else {
        const int g2 = g - 768 * 256;
        const int o = g2 >> 8, cc = g2 & 255;
        const float v = wo[(size_t)o * 256 + cc];
        const short hi = f2bf(v);
        const short lo = f2bf(v - bf2f(hi));
        WoA[(size_t)o * 512 + cc]       = hi;
        WoA[(size_t)o * 512 + 256 + cc] = lo;
    }
}

// ---------------------------------------------------------------------------
// MFMA GEMM (m97 structure): D[M-tile 128][L-tile 128] = A[M][K] * B(t)[l][k]
// Both K-phases read B0 (hi); KTOT=512 everywhere now.
// ---------------------------------------------------------------------------
template <int KTOT, int EPI>
__global__ __launch_bounds__(256, 2) void gemm_kernel(
    const short* __restrict__ A, const short* __restrict__ B0,
    const float* __restrict__ bias0, const float* __restrict__ bias1, const float* __restrict__ bias2,
    float qscale, void* __restrict__ out0, void* __restrict__ out1, void* __restrict__ out2)
{
    const int lt = blockIdx.x, ot = blockIdx.y, b = blockIdx.z;
    const int t = threadIdx.x, wv = t >> 6, lane = t & 63;
    const int quad = lane >> 4, c = lane & 15;
    const int wo = (wv & 1) * 64, wl = (wv >> 1) * 64;

    __shared__ short sA[128 * 32];   // [row][k], 64B rows, glds-contiguous
    __shared__ short sB[128 * 32];

    float4v acc[4][4];
#pragma unroll
    for (int i = 0; i < 4; ++i)
#pragma unroll
        for (int j = 0; j < 4; ++j) acc[i][j] = (float4v)0.f;

    const short* Arow = A + (size_t)(ot * 128) * KTOT;
    const int srow = t >> 2, sseg = t & 3;          // staging: 4 lanes x 16B per row

    for (int kk = 0; kk < KTOT / 32; ++kk) {
        const int koff = (kk & 7) * 32;             // within the 256-wide phase
        __syncthreads();
#pragma unroll
        for (int e = 0; e < 2; ++e) {
            gld16(Arow + (size_t)(e * 64 + srow) * KTOT + kk * 32 + sseg * 8,
                  &sA[(e * 256 + t) * 8]);
            gld16(B0 + ((size_t)b * L_ + lt * 128 + e * 64 + srow) * 256 + koff + sseg * 8,
                  &sB[(e * 256 + t) * 8]);
        }
        __syncthreads();

        short8v af[4], bf[4];
#pragma unroll
        for (int i = 0; i < 4; ++i) af[i] = *(const short8v*)&sA[(wo + 16 * i + c) * 32 + quad * 8];
#pragma unroll
        for (int j = 0; j < 4; ++j) bf[j] = *(const short8v*)&sB[(wl + 16 * j + c) * 32 + quad * 8];
#pragma unroll
        for (int i = 0; i < 4; ++i)
#pragma unroll
            for (int j = 0; j < 4; ++j)
                acc[i][j] = __builtin_amdgcn_mfma_f32_16x16x32_bf16(af[i], bf[j], acc[i][j], 0, 0, 0);
    }

    if constexpr (EPI == 0) {
        const int typ = ot >> 1;                     // 0=q 1=k 2=v
        const int chbase = (ot & 1) * 128 + wo;
        const float* bp = (typ == 0) ? bias0 : (typ == 1) ? bias1 : bias2;
        const float sc = (typ == 0) ? qscale : 1.f;
        short* outp = (short*)((typ == 0) ? out0 : (typ == 1) ? out1 : out2);
        if (typ < 2) {
            // q/k -> [b][h][l][d] bf16, short4 packed over r (consecutive d)
#pragma unroll
            for (int i = 0; i < 4; ++i) {
                const int ch0 = chbase + 16 * i + quad * 4;
                const int head = ch0 >> 5, d0 = ch0 & 31;
                float bias[4];
#pragma unroll
                for (int r = 0; r < 4; ++r) bias[r] = bp[ch0 + r];
#pragma unroll
                for (int j = 0; j < 4; ++j) {
                    const int l = lt * 128 + wl + 16 * j + c;
                    short4 sv;
                    sv.x = f2bf((acc[i][j][0] + bias[0]) * sc);
                    sv.y = f2bf((acc[i][j][1] + bias[1]) * sc);
                    sv.z = f2bf((acc[i][j][2] + bias[2]) * sc);
                    sv.w = f2bf((acc[i][j][3] + bias[3]) * sc);
                    *(short4*)&outp[(((size_t)b * NH_ + head) * L_ + l) * 32 + d0] = sv;
                }
            }
        } else {
            // v -> [b][c][l] bf16
#pragma unroll
            for (int i = 0; i < 4; ++i)
#pragma unroll
                for (int r = 0; r < 4; ++r) {
                    const int ch = chbase + 16 * i + quad * 4 + r;
                    const float bias = bp[ch];
#pragma unroll
                    for (int j = 0; j < 4; ++j)
                        outp[((size_t)b * C_ + ch) * L_ + lt * 128 + wl + 16 * j + c] =
                            f2bf(acc[i][j][r] + bias);
                }
        }
    } else {
        float* outp = (float*)out0;
#pragma unroll
        for (int i = 0; i < 4; ++i)
#pragma unroll
            for (int r = 0; r < 4; ++r) {
                const int ch = ot * 128 + wo + 16 * i + quad * 4 + r;
                const float bias = bias0[ch];
#pragma unroll
                for (int j = 0; j < 4; ++j)
                    outp[((size_t)b * C_ + ch) * L_ + lt * 128 + wl + 16 * j + c] =
                        acc[i][j][r] + bias;
            }
    }
}

// ---------------------------------------------------------------------------
// MFMA flash attention, S^T form, XCD-swizzled, 32 q/wave, shared LDS K/V
// (m97 pattern): per tile, the block stages K (4 KB) + V (4 KB) once via
// global_load_lds, double-buffered; one barrier per tile; fragment reads are
// ds_read_b128 (~30 cyc) instead of per-wave L2 loads (~200+ cyc).
// ---------------------------------------------------------------------------
__global__ __launch_bounds__(256, 4) void attn_kernel(
    const short* __restrict__ qt,   // [b][h][l][d] bf16 (scale*log2e folded)
    const short* __restrict__ kt,   // [b][h][l][d] bf16
    const short* __restrict__ vb,   // [b][c][l]    bf16
    short* __restrict__ athi)       // [b][l][c]    bf16
{
    const int flat = blockIdx.x;
    const int g = ((flat >> 6) << 3) | (flat & 7);  // (b,h) group
    const int chunk = (flat >> 3) & 7;
    const int b = g >> 3, h = g & 7;
    const int t = threadIdx.x;
    const int wv = t >> 6, lane = t & 63;
    const int quad = lane >> 4, c = lane & 15;
    const int lq0 = chunk * 128 + wv * 32;          // wave's 32 queries

    __shared__ __align__(16) short sK[2][64 * 32];      // [key][d], 64B rows
    __shared__ __align__(16) short sV[2][2][32 * 32];   // [kc][ch][key32], 64B rows
    __shared__ __align__(16) short sPT[4][2][16][72];   // per-wave P^T

    const size_t bh = (size_t)b * NH_ + h;
    const short* qbase = qt + (bh * L_) * 32;
    const short* kbase = kt + (bh * L_) * 32;
    const size_t vrow = (size_t)b * C_ + h * DH_;

    short8v qfrag[2];
#pragma unroll
    for (int qf = 0; qf < 2; ++qf)
        qfrag[qf] = *(const short8v*)(qbase + (size_t)(lq0 + qf * 16 + c) * 32 + quad * 8);

    float lp4[2][4];
#pragma unroll
    for (int qf = 0; qf < 2; ++qf)
#pragma unroll
        for (int r = 0; r < 4; ++r) lp4[qf][r] = 0.f;
    float4v o_acc[2][2];
#pragma unroll
    for (int qf = 0; qf < 2; ++qf) { o_acc[qf][0] = (float4v)0.f; o_acc[qf][1] = (float4v)0.f; }

    // cooperative staging: K rows key=t>>2 (d-seg t&3), V rows ch=(t>>2)&31
    // (kc=t>>7, key-seg t&3); LDS dest = tid*16B (lane-contiguous per wave)
    auto stage = [&](int m0, int buf) {
        gld16(kbase + (size_t)(m0 + (t >> 2)) * 32 + (t & 3) * 8, &sK[buf][t * 8]);
        gld16(vb + (vrow + ((t >> 2) & 31)) * L_ + m0 + (t >> 7) * 32 + (t & 3) * 8,
              (short*)sV[buf] + t * 8);
    };

    stage(0, 0);

    for (int i = 0; i < 16; ++i) {
        __syncthreads();                 // staging of tile i visible; buf (i+1)&1 free
        if (i < 15) stage((i + 1) * 64, (i + 1) & 1);
        const int buf = i & 1;

        short8v kf[4], vf[2][2];
#pragma unroll
        for (int kb = 0; kb < 4; ++kb)
            kf[kb] = *(const short8v*)&sK[buf][(kb * 16 + c) * 32 + quad * 8];
#pragma unroll
        for (int kc = 0; kc < 2; ++kc)
#pragma unroll
            for (int nb2 = 0; nb2 < 2; ++nb2)
                vf[kc][nb2] = *(const short8v*)&sV[buf][kc][(nb2 * 16 + c) * 32 + quad * 8];

        // S^T = K Q^T
        float4v st[2][4];
#pragma unroll
        for (int qf = 0; qf < 2; ++qf)
#pragma unroll
            for (int kb = 0; kb < 4; ++kb)
                st[qf][kb] = __builtin_amdgcn_mfma_f32_16x16x32_bf16(kf[kb], qfrag[qf], (float4v)0.f, 0, 0, 0);

        // p = exp2(s); 4 independent denom partials per qf; P^T -> LDS
#pragma unroll
        for (int qf = 0; qf < 2; ++qf)
#pragma unroll
            for (int kb = 0; kb < 4; ++kb) {
                float p[4];
#pragma unroll
                for (int r = 0; r < 4; ++r) {
                    p[r] = __builtin_amdgcn_exp2f(st[qf][kb][r]);
                    lp4[qf][r] += p[r];
                }
                uint2 w;
                w.x = pkrn(p[0], p[1]);
                w.y = pkrn(p[2], p[3]);
                *(uint2*)&sPT[wv][qf][c][kb * 16 + quad * 4] = w;
            }

        // O += V P^T
#pragma unroll
        for (int qf = 0; qf < 2; ++qf)
#pragma unroll
            for (int kc = 0; kc < 2; ++kc) {
                const short8v pf = *(const short8v*)&sPT[wv][qf][c][kc * 32 + quad * 8];
#pragma unroll
                for (int nb2 = 0; nb2 < 2; ++nb2)
                    o_acc[qf][nb2] = __builtin_amdgcn_mfma_f32_16x16x32_bf16(vf[kc][nb2], pf, o_acc[qf][nb2], 0, 0, 0);
            }
    }

#pragma unroll
    for (int qf = 0; qf < 2; ++qf) {
        float l = (lp4[qf][0] + lp4[qf][1]) + (lp4[qf][2] + lp4[qf][3]);
        l += __shfl_xor(l, 16);
        l += __shfl_xor(l, 32);
        const float inv = 1.f / l;
        // At[b][l][c]: l = lq0 + qf*16 + c, ch = h*32 + nb2*16 + quad*4 + r
#pragma unroll
        for (int nb2 = 0; nb2 < 2; ++nb2) {
            short4 sv;
            sv.x = f2bf(o_acc[qf][nb2][0] * inv);
            sv.y = f2bf(o_acc[qf][nb2][1] * inv);
            sv.z = f2bf(o_acc[qf][nb2][2] * inv);
            sv.w = f2bf(o_acc[qf][nb2][3] * inv);
            *(short4*)&athi[((size_t)b * L_ + lq0 + qf * 16 + c) * C_ + h * DH_ + nb2 * 16 + quad * 4] = sv;
        }
    }
}

}  // namespace

extern "C" void kernel_launch(void* const* d_in, const int* in_sizes, int n_in,
                              void* d_out, int out_size, void* d_ws, size_t ws_size,
                              hipStream_t stream) {
    const float* x   = (const float*)d_in[0];
    const float* w_q = (const float*)d_in[1];
    const float* b_q = (const float*)d_in[2];
    const float* w_k = (const float*)d_in[3];
    const float* b_k = (const float*)d_in[4];
    const float* w_v = (const float*)d_in[5];
    const float* b_v = (const float*)d_in[6];
    const float* w_o = (const float*)d_in[7];
    const float* b_o = (const float*)d_in[8];
    float* out = (float*)d_out;

    // workspace (shorts): Xthi | WA | WoA | qt | kt | vb | Athi  ~43 MB
    const size_t NT = (size_t)B_ * L_ * C_;   // 4,194,304
    short* xthi = (short*)d_ws;
    short* WA   = xthi + NT;                  // 768*512
    short* WoA  = WA + 768 * 512;             // 256*512
    short* qt   = WoA + 256 * 512;
    short* kt   = qt + NT;
    short* vb   = kt + NT;
    short* athi = vb + NT;

    const float scale_q = 0.17677669529663687f * 1.4426950408889634f; // 1/sqrt(32)*log2(e)

    xpose_kernel<<<dim3(L_ / 64, C_ / 64, B_), 256, 0, stream>>>(x, xthi);
    stackw_kernel<<<dim3(1024), 256, 0, stream>>>(w_q, w_k, w_v, w_o, WA, WoA);
    gemm_kernel<512, 0><<<dim3(L_ / 128, 6, B_), 256, 0, stream>>>(
        WA, xthi, b_q, b_k, b_v, scale_q, qt, kt, vb);
    attn_kernel<<<dim3(1024), 256, 0, stream>>>(qt, kt, vb, athi);
    gemm_kernel<512, 1><<<dim3(L_ / 128, 2, B_), 256, 0, stream>>>(
        WoA, athi, b_o, nullptr, nullptr, 1.f, out, nullptr, nullptr);
}

// Round 9
// 152.864 us; speedup vs baseline: 1.2073x; 1.0125x over previous
//
#include <hip/hip_runtime.h>
#include <hip/hip_bf16.h>
#include <math.h>

namespace {
constexpr int B_ = 16, C_ = 256, L_ = 1024, NH_ = 8, DH_ = 32;

typedef __attribute__((ext_vector_type(8))) short short8v;   // 8 bf16
typedef __attribute__((ext_vector_type(4))) float float4v;   // 4 fp32

// fp32 -> bf16 RNE
__device__ __forceinline__ short f2bf(float f) {
    unsigned u = __builtin_bit_cast(unsigned, f);
    u += 0x7fffu + ((u >> 16) & 1u);
    return (short)(u >> 16);
}
__device__ __forceinline__ float bf2f(short s) {
    unsigned u = ((unsigned)(unsigned short)s) << 16;
    return __builtin_bit_cast(float, u);
}
// packed fp32x2 -> bf16x2 (v_cvt_pk_bf16_f32 on gfx950), a in low half
__device__ __forceinline__ unsigned pkrn(float a, float b) {
    float2 f; f.x = a; f.y = b;
    __hip_bfloat162 h = __float22bfloat162_rn(f);
    unsigned u;
    __builtin_memcpy(&u, &h, sizeof(u));
    return u;
}
// async global->LDS, 16B per lane; LDS dest is wave-base + lane*16 (forced)
__device__ __forceinline__ void gld16(const short* g, short* l) {
    __builtin_amdgcn_global_load_lds(
        (const __attribute__((address_space(1))) unsigned*)g,
        (__attribute__((address_space(3))) unsigned*)l, 16, 0, 0);
}

// ---------------------------------------------------------------------------
// x [b][c][l] fp32  ->  Xt hi bf16 [b][l][c]   (64x64 LDS transpose tiles)
// ---------------------------------------------------------------------------
__global__ __launch_bounds__(256) void xpose_kernel(
    const float* __restrict__ x, short* __restrict__ xthi)
{
    const int lt = blockIdx.x, ct = blockIdx.y, b = blockIdx.z;
    const int t = threadIdx.x;
    __shared__ float sX[64][68];

#pragma unroll
    for (int e = 0; e < 4; ++e) {
        const int row = e * 16 + (t >> 4);          // local c
        const int col = (t & 15) * 4;               // local l
        float4 v = *(const float4*)&x[((size_t)b * C_ + ct * 64 + row) * L_ + lt * 64 + col];
        *(float4*)&sX[row][col] = v;
    }
    __syncthreads();

    const int l = t & 63, cg = t >> 6;              // 16 channels per thread
    short hi[16];
#pragma unroll
    for (int i = 0; i < 16; ++i) hi[i] = f2bf(sX[cg * 16 + i][l]);
    const size_t base = ((size_t)b * L_ + lt * 64 + l) * C_ + ct * 64 + cg * 16;
    *(short8v*)&xthi[base]     = *(short8v*)&hi[0];
    *(short8v*)&xthi[base + 8] = *(short8v*)&hi[8];
}

// ---------------------------------------------------------------------------
// Stack weights: WA [768][512] = [Whi|Wlo] rows {q,k,v}; WoA [256][512]
// ---------------------------------------------------------------------------
__global__ __launch_bounds__(256) void stackw_kernel(
    const float* __restrict__ wq, const float* __restrict__ wk,
    const float* __restrict__ wv, const float* __restrict__ wo,
    short* __restrict__ WA, short* __restrict__ WoA)
{
    const int g = blockIdx.x * 256 + threadIdx.x;
    if (g < 768 * 256) {
        const int o = g >> 8, cc = g & 255;
        const float* src = (o < 256) ? wq : (o < 512) ? wk : wv;
        const float v = src[(size_t)(o & 255) * 256 + cc];
        const short hi = f2bf(v);
        const short lo = f2bf(v - bf2f(hi));
        WA[(size_t)o * 512 + cc]       = hi;
        WA[(size_t)o * 512 + 256 + cc] = lo;
    } else {
        const int g2 = g - 768 * 256;
        const int o = g2 >> 8, cc = g2 & 255;
        const float v = wo[(size_t)o * 256 + cc];
        const short hi = f2bf(v);
        const short lo = f2bf(v - bf2f(hi));
        WoA[(size_t)o * 512 + cc]       = hi;
        WoA[(size_t)o * 512 + 256 + cc] = lo;
    }
}

// ---------------------------------------------------------------------------
// MFMA GEMM, BK=64 (8 barriers, 32 MFMA/barrier), XOR-swizzled staging.
// LDS rows 128 B; k-segment stored at pos = seg ^ (row&7) so fragment reads
// hit all 32 banks (2-way alias only). B column index wraps mod 256 (the
// hi/lo K-phases both read B0).
// ---------------------------------------------------------------------------
template <int KTOT, int EPI>
__global__ __launch_bounds__(256, 3) void gemm_kernel(
    const short* __restrict__ A, const short* __restrict__ B0,
    const float* __restrict__ bias0, const float* __restrict__ bias1, const float* __restrict__ bias2,
    float qscale, void* __restrict__ out0, void* __restrict__ out1, void* __restrict__ out2)
{
    const int lt = blockIdx.x, ot = blockIdx.y, b = blockIdx.z;
    const int t = threadIdx.x, wv = t >> 6, lane = t & 63;
    const int quad = lane >> 4, c = lane & 15;
    const int wo = (wv & 1) * 64, wl = (wv >> 1) * 64;

    __shared__ short sA[128 * 64];   // [row][k64], swizzled segments
    __shared__ short sB[128 * 64];

    float4v acc[4][4];
#pragma unroll
    for (int i = 0; i < 4; ++i)
#pragma unroll
        for (int j = 0; j < 4; ++j) acc[i][j] = (float4v)0.f;

    const short* Arow = A + (size_t)(ot * 128) * KTOT;
    const int srow = t >> 3, sseg = t & 7;
    const int seg = sseg ^ (srow & 7);              // source-side swizzle

    for (int kk = 0; kk < KTOT / 64; ++kk) {
        __syncthreads();
#pragma unroll
        for (int e = 0; e < 4; ++e) {
            gld16(Arow + (size_t)(e * 32 + srow) * KTOT + kk * 64 + seg * 8,
                  &sA[(e * 256 + t) * 8]);
            gld16(B0 + ((size_t)b * L_ + lt * 128 + e * 32 + srow) * 256 + (kk & 3) * 64 + seg * 8,
                  &sB[(e * 256 + t) * 8]);
        }
        __syncthreads();

#pragma unroll
        for (int kc2 = 0; kc2 < 2; ++kc2) {
            short8v af[4], bf[4];
#pragma unroll
            for (int i = 0; i < 4; ++i) {
                const int row = wo + 16 * i + c;
                af[i] = *(const short8v*)&sA[row * 64 + (((kc2 * 4 + quad) ^ (c & 7)) * 8)];
            }
#pragma unroll
            for (int j = 0; j < 4; ++j) {
                const int row = wl + 16 * j + c;
                bf[j] = *(const short8v*)&sB[row * 64 + (((kc2 * 4 + quad) ^ (c & 7)) * 8)];
            }
#pragma unroll
            for (int i = 0; i < 4; ++i)
#pragma unroll
                for (int j = 0; j < 4; ++j)
                    acc[i][j] = __builtin_amdgcn_mfma_f32_16x16x32_bf16(af[i], bf[j], acc[i][j], 0, 0, 0);
        }
    }

    if constexpr (EPI == 0) {
        const int typ = ot >> 1;                     // 0=q 1=k 2=v
        const int chbase = (ot & 1) * 128 + wo;
        const float* bp = (typ == 0) ? bias0 : (typ == 1) ? bias1 : bias2;
        const float sc = (typ == 0) ? qscale : 1.f;
        short* outp = (short*)((typ == 0) ? out0 : (typ == 1) ? out1 : out2);
        if (typ < 2) {
#pragma unroll
            for (int i = 0; i < 4; ++i) {
                const int ch0 = chbase + 16 * i + quad * 4;
                const int head = ch0 >> 5, d0 = ch0 & 31;
                float bias[4];
#pragma unroll
                for (int r = 0; r < 4; ++r) bias[r] = bp[ch0 + r];
#pragma unroll
                for (int j = 0; j < 4; ++j) {
                    const int l = lt * 128 + wl + 16 * j + c;
                    short4 sv;
                    sv.x = f2bf((acc[i][j][0] + bias[0]) * sc);
                    sv.y = f2bf((acc[i][j][1] + bias[1]) * sc);
                    sv.z = f2bf((acc[i][j][2] + bias[2]) * sc);
                    sv.w = f2bf((acc[i][j][3] + bias[3]) * sc);
                    *(short4*)&outp[(((size_t)b * NH_ + head) * L_ + l) * 32 + d0] = sv;
                }
            }
        } else {
#pragma unroll
            for (int i = 0; i < 4; ++i)
#pragma unroll
                for (int r = 0; r < 4; ++r) {
                    const int ch = chbase + 16 * i + quad * 4 + r;
                    const float bias = bp[ch];
#pragma unroll
                    for (int j = 0; j < 4; ++j)
                        outp[((size_t)b * C_ + ch) * L_ + lt * 128 + wl + 16 * j + c] =
                            f2bf(acc[i][j][r] + bias);
                }
        }
    } else {
        float* outp = (float*)out0;
#pragma unroll
        for (int i = 0; i < 4; ++i)
#pragma unroll
            for (int r = 0; r < 4; ++r) {
                const int ch = ot * 128 + wo + 16 * i + quad * 4 + r;
                const float bias = bias0[ch];
#pragma unroll
                for (int j = 0; j < 4; ++j)
                    outp[((size_t)b * C_ + ch) * L_ + lt * 128 + wl + 16 * j + c] =
                        acc[i][j][r] + bias;
            }
    }
}

// ---------------------------------------------------------------------------
// MFMA flash attention: 128-key super-tiles (8 barriers), double-buffered
// LDS K/V staging, two 64-key sub-tiles per window (sub1 S-chain overlaps
// sub0 PV-chain). V staged with 16-pos XOR swizzle (rows 256 B would be
// bank-degenerate); K with 4-pos swizzle.
// ---------------------------------------------------------------------------
__global__ __launch_bounds__(256, 4) void attn_kernel(
    const short* __restrict__ qt,   // [b][h][l][d] bf16 (scale*log2e folded)
    const short* __restrict__ kt,   // [b][h][l][d] bf16
    const short* __restrict__ vb,   // [b][c][l]    bf16
    short* __restrict__ athi)       // [b][l][c]    bf16
{
    const int flat = blockIdx.x;
    const int g = ((flat >> 6) << 3) | (flat & 7);  // (b,h) group
    const int chunk = (flat >> 3) & 7;
    const int b = g >> 3, h = g & 7;
    const int t = threadIdx.x;
    const int wv = t >> 6, lane = t & 63;
    const int quad = lane >> 4, c = lane & 15;
    const int lq0 = chunk * 128 + wv * 32;          // wave's 32 queries

    __shared__ __align__(16) short sK[2][128 * 32];     // [key][d], 4-pos swizzle
    __shared__ __align__(16) short sV[2][32 * 128];     // [ch][key], 16-pos swizzle
    __shared__ __align__(16) short sPT[4][2][16][72];   // per-wave P^T

    const size_t bh = (size_t)b * NH_ + h;
    const short* qbase = qt + (bh * L_) * 32;
    const short* kbase = kt + (bh * L_) * 32;
    const size_t vrow = (size_t)b * C_ + h * DH_;

    short8v qfrag[2];
#pragma unroll
    for (int qf = 0; qf < 2; ++qf)
        qfrag[qf] = *(const short8v*)(qbase + (size_t)(lq0 + qf * 16 + c) * 32 + quad * 8);

    float lp4[2][4];
#pragma unroll
    for (int qf = 0; qf < 2; ++qf)
#pragma unroll
        for (int r = 0; r < 4; ++r) lp4[qf][r] = 0.f;
    float4v o_acc[2][2];
#pragma unroll
    for (int qf = 0; qf < 2; ++qf) { o_acc[qf][0] = (float4v)0.f; o_acc[qf][1] = (float4v)0.f; }

    // staging: 128 keys per super-tile. LDS dest is forced to waveBase+lane*16;
    // swizzle is applied on the GLOBAL source segment index.
    auto stage = [&](int m0, int buf) {
        // K: 128 rows x 32 d; row = e*64 + t>>2; pos = t&3 -> seg = pos^(row&3)
#pragma unroll
        for (int e = 0; e < 2; ++e) {
            const int row = e * 64 + (t >> 2);
            const int sg = (t & 3) ^ (row & 3);
            gld16(kbase + (size_t)(m0 + row) * 32 + sg * 8, &sK[buf][(e * 256 + t) * 8]);
        }
        // V: 32 ch x 128 keys; ch = e*16 + wv*4 + (lane>>4); pos = lane&15
#pragma unroll
        for (int e = 0; e < 2; ++e) {
            const int ch = e * 16 + wv * 4 + (lane >> 4);
            const int sg = (lane & 15) ^ (ch & 15);
            gld16(vb + (vrow + ch) * L_ + m0 + sg * 8, &sV[buf][(e * 256 + t) * 8]);
        }
    };

    stage(0, 0);

    for (int i = 0; i < 8; ++i) {
        __syncthreads();
        if (i < 7) stage((i + 1) * 128, (i + 1) & 1);
        const int buf = i & 1;

#pragma unroll
        for (int sub = 0; sub < 2; ++sub) {
            short8v kf[4], vf[2][2];
#pragma unroll
            for (int kb = 0; kb < 4; ++kb) {
                const int row = sub * 64 + kb * 16 + c;
                kf[kb] = *(const short8v*)&sK[buf][row * 32 + ((quad ^ (c & 3)) * 8)];
            }
#pragma unroll
            for (int kcL = 0; kcL < 2; ++kcL)
#pragma unroll
                for (int nb2 = 0; nb2 < 2; ++nb2) {
                    const int pos = (sub * 8 + kcL * 4 + quad) ^ c;
                    vf[kcL][nb2] = *(const short8v*)&sV[buf][(nb2 * 16 + c) * 128 + pos * 8];
                }

            // S^T = K Q^T
            float4v st[2][4];
#pragma unroll
            for (int qf = 0; qf < 2; ++qf)
#pragma unroll
                for (int kb = 0; kb < 4; ++kb)
                    st[qf][kb] = __builtin_amdgcn_mfma_f32_16x16x32_bf16(kf[kb], qfrag[qf], (float4v)0.f, 0, 0, 0);

            // p = exp2(s); 4 independent denom partials per qf; P^T -> LDS
#pragma unroll
            for (int qf = 0; qf < 2; ++qf)
#pragma unroll
                for (int kb = 0; kb < 4; ++kb) {
                    float p[4];
#pragma unroll
                    for (int r = 0; r < 4; ++r) {
                        p[r] = __builtin_amdgcn_exp2f(st[qf][kb][r]);
                        lp4[qf][r] += p[r];
                    }
                    uint2 w;
                    w.x = pkrn(p[0], p[1]);
                    w.y = pkrn(p[2], p[3]);
                    *(uint2*)&sPT[wv][qf][c][kb * 16 + quad * 4] = w;
                }

            // O += V P^T
#pragma unroll
            for (int qf = 0; qf < 2; ++qf)
#pragma unroll
                for (int kcL = 0; kcL < 2; ++kcL) {
                    const short8v pf = *(const short8v*)&sPT[wv][qf][c][kcL * 32 + quad * 8];
#pragma unroll
                    for (int nb2 = 0; nb2 < 2; ++nb2)
                        o_acc[qf][nb2] = __builtin_amdgcn_mfma_f32_16x16x32_bf16(vf[kcL][nb2], pf, o_acc[qf][nb2], 0, 0, 0);
                }
        }
    }

#pragma unroll
    for (int qf = 0; qf < 2; ++qf) {
        float l = (lp4[qf][0] + lp4[qf][1]) + (lp4[qf][2] + lp4[qf][3]);
        l += __shfl_xor(l, 16);
        l += __shfl_xor(l, 32);
        const float inv = 1.f / l;
#pragma unroll
        for (int nb2 = 0; nb2 < 2; ++nb2) {
            short4 sv;
            sv.x = f2bf(o_acc[qf][nb2][0] * inv);
            sv.y = f2bf(o_acc[qf][nb2][1] * inv);
            sv.z = f2bf(o_acc[qf][nb2][2] * inv);
            sv.w = f2bf(o_acc[qf][nb2][3] * inv);
            *(short4*)&athi[((size_t)b * L_ + lq0 + qf * 16 + c) * C_ + h * DH_ + nb2 * 16 + quad * 4] = sv;
        }
    }
}

}  // namespace

extern "C" void kernel_launch(void* const* d_in, const int* in_sizes, int n_in,
                              void* d_out, int out_size, void* d_ws, size_t ws_size,
                              hipStream_t stream) {
    const float* x   = (const float*)d_in[0];
    const float* w_q = (const float*)d_in[1];
    const float* b_q = (const float*)d_in[2];
    const float* w_k = (const float*)d_in[3];
    const float* b_k = (const float*)d_in[4];
    const float* w_v = (const float*)d_in[5];
    const float* b_v = (const float*)d_in[6];
    const float* w_o = (const float*)d_in[7];
    const float* b_o = (const float*)d_in[8];
    float* out = (float*)d_out;

    const size_t NT = (size_t)B_ * L_ * C_;   // 4,194,304
    short* xthi = (short*)d_ws;
    short* WA   = xthi + NT;                  // 768*512
    short* WoA  = WA + 768 * 512;             // 256*512
    short* qt   = WoA + 256 * 512;
    short* kt   = qt + NT;
    short* vb   = kt + NT;
    short* athi = vb + NT;

    const float scale_q = 0.17677669529663687f * 1.4426950408889634f; // 1/sqrt(32)*log2(e)

    xpose_kernel<<<dim3(L_ / 64, C_ / 64, B_), 256, 0, stream>>>(x, xthi);
    stackw_kernel<<<dim3(1024), 256, 0, stream>>>(w_q, w_k, w_v, w_o, WA, WoA);
    gemm_kernel<512, 0><<<dim3(L_ / 128, 6, B_), 256, 0, stream>>>(
        WA, xthi, b_q, b_k, b_v, scale_q, qt, kt, vb);
    attn_kernel<<<dim3(1024), 256, 0, stream>>>(qt, kt, vb, athi);
    gemm_kernel<512, 1><<<dim3(L_ / 128, 2, B_), 256, 0, stream>>>(
        WoA, athi, b_o, nullptr, nullptr, 1.f, out, nullptr, nullptr);
}

// Round 10
// 151.287 us; speedup vs baseline: 1.2199x; 1.0104x over previous
//
#include <hip/hip_runtime.h>
#include <hip/hip_bf16.h>
#include <math.h>

namespace {
constexpr int B_ = 16, C_ = 256, L_ = 1024, NH_ = 8, DH_ = 32;

typedef __attribute__((ext_vector_type(8))) short short8v;   // 8 bf16
typedef __attribute__((ext_vector_type(4))) float float4v;   // 4 fp32

// fp32 -> bf16 RNE
__device__ __forceinline__ short f2bf(float f) {
    unsigned u = __builtin_bit_cast(unsigned, f);
    u += 0x7fffu + ((u >> 16) & 1u);
    return (short)(u >> 16);
}
__device__ __forceinline__ float bf2f(short s) {
    unsigned u = ((unsigned)(unsigned short)s) << 16;
    return __builtin_bit_cast(float, u);
}
// packed fp32x2 -> bf16x2 (v_cvt_pk_bf16_f32 on gfx950), a in low half
__device__ __forceinline__ unsigned pkrn(float a, float b) {
    float2 f; f.x = a; f.y = b;
    __hip_bfloat162 h = __float22bfloat162_rn(f);
    unsigned u;
    __builtin_memcpy(&u, &h, sizeof(u));
    return u;
}
// async global->LDS, 16B per lane; LDS dest is wave-base + lane*16 (forced)
__device__ __forceinline__ void gld16(const short* g, short* l) {
    __builtin_amdgcn_global_load_lds(
        (const __attribute__((address_space(1))) unsigned*)g,
        (__attribute__((address_space(3))) unsigned*)l, 16, 0, 0);
}

// ---------------------------------------------------------------------------
// x [b][c][l] fp32  ->  Xt hi bf16 [b][l][c]   (64x64 LDS transpose tiles)
// ---------------------------------------------------------------------------
__global__ __launch_bounds__(256) void xpose_kernel(
    const float* __restrict__ x, short* __restrict__ xthi)
{
    const int lt = blockIdx.x, ct = blockIdx.y, b = blockIdx.z;
    const int t = threadIdx.x;
    __shared__ float sX[64][68];

#pragma unroll
    for (int e = 0; e < 4; ++e) {
        const int row = e * 16 + (t >> 4);          // local c
        const int col = (t & 15) * 4;               // local l
        float4 v = *(const float4*)&x[((size_t)b * C_ + ct * 64 + row) * L_ + lt * 64 + col];
        *(float4*)&sX[row][col] = v;
    }
    __syncthreads();

    const int l = t & 63, cg = t >> 6;              // 16 channels per thread
    short hi[16];
#pragma unroll
    for (int i = 0; i < 16; ++i) hi[i] = f2bf(sX[cg * 16 + i][l]);
    const size_t base = ((size_t)b * L_ + lt * 64 + l) * C_ + ct * 64 + cg * 16;
    *(short8v*)&xthi[base]     = *(short8v*)&hi[0];
    *(short8v*)&xthi[base + 8] = *(short8v*)&hi[8];
}

// ---------------------------------------------------------------------------
// Stack weights: WA [768][512] = [Whi|Wlo] rows {q,k,v}; WoA [256][512]
// ---------------------------------------------------------------------------
__global__ __launch_bounds__(256) void stackw_kernel(
    const float* __restrict__ wq, const float* __restrict__ wk,
    const float* __restrict__ wv, const float* __restrict__ wo,
    short* __restrict__ WA, short* __restrict__ WoA)
{
    const int g = blockIdx.x * 256 + threadIdx.x;
    if (g < 768 * 256) {
        const int o = g >> 8, cc = g & 255;
        const float* src = (o < 256) ? wq : (o < 512) ? wk : wv;
        const float v = src[(size_t)(o & 255) * 256 + cc];
        const short hi = f2bf(v);
        const short lo = f2bf(v - bf2f(hi));
        WA[(size_t)o * 512 + cc]       = hi;
        WA[(size_t)o * 512 + 256 + cc] = lo;
    } else {
        const int g2 = g - 768 * 256;
        const int o = g2 >> 8, cc = g2 & 255;
        const float v = wo[(size_t)o * 256 + cc];
        const short hi = f2bf(v);
        const short lo = f2bf(v - bf2f(hi));
        WoA[(size_t)o * 512 + cc]       = hi;
        WoA[(size_t)o * 512 + 256 + cc] = lo;
    }
}

// ---------------------------------------------------------------------------
// MFMA GEMM, BK=64 (8 barriers, 32 MFMA/barrier), XOR-swizzled staging.
// ---------------------------------------------------------------------------
template <int KTOT, int EPI>
__global__ __launch_bounds__(256, 3) void gemm_kernel(
    const short* __restrict__ A, const short* __restrict__ B0,
    const float* __restrict__ bias0, const float* __restrict__ bias1, const float* __restrict__ bias2,
    float qscale, void* __restrict__ out0, void* __restrict__ out1, void* __restrict__ out2)
{
    const int lt = blockIdx.x, ot = blockIdx.y, b = blockIdx.z;
    const int t = threadIdx.x, wv = t >> 6, lane = t & 63;
    const int quad = lane >> 4, c = lane & 15;
    const int wo = (wv & 1) * 64, wl = (wv >> 1) * 64;

    __shared__ short sA[128 * 64];   // [row][k64], swizzled segments
    __shared__ short sB[128 * 64];

    float4v acc[4][4];
#pragma unroll
    for (int i = 0; i < 4; ++i)
#pragma unroll
        for (int j = 0; j < 4; ++j) acc[i][j] = (float4v)0.f;

    const short* Arow = A + (size_t)(ot * 128) * KTOT;
    const int srow = t >> 3, sseg = t & 7;
    const int seg = sseg ^ (srow & 7);              // source-side swizzle

    for (int kk = 0; kk < KTOT / 64; ++kk) {
        __syncthreads();
#pragma unroll
        for (int e = 0; e < 4; ++e) {
            gld16(Arow + (size_t)(e * 32 + srow) * KTOT + kk * 64 + seg * 8,
                  &sA[(e * 256 + t) * 8]);
            gld16(B0 + ((size_t)b * L_ + lt * 128 + e * 32 + srow) * 256 + (kk & 3) * 64 + seg * 8,
                  &sB[(e * 256 + t) * 8]);
        }
        __syncthreads();

#pragma unroll
        for (int kc2 = 0; kc2 < 2; ++kc2) {
            short8v af[4], bf[4];
#pragma unroll
            for (int i = 0; i < 4; ++i) {
                const int row = wo + 16 * i + c;
                af[i] = *(const short8v*)&sA[row * 64 + (((kc2 * 4 + quad) ^ (c & 7)) * 8)];
            }
#pragma unroll
            for (int j = 0; j < 4; ++j) {
                const int row = wl + 16 * j + c;
                bf[j] = *(const short8v*)&sB[row * 64 + (((kc2 * 4 + quad) ^ (c & 7)) * 8)];
            }
#pragma unroll
            for (int i = 0; i < 4; ++i)
#pragma unroll
                for (int j = 0; j < 4; ++j)
                    acc[i][j] = __builtin_amdgcn_mfma_f32_16x16x32_bf16(af[i], bf[j], acc[i][j], 0, 0, 0);
        }
    }

    if constexpr (EPI == 0) {
        const int typ = ot >> 1;                     // 0=q 1=k 2=v
        const int chbase = (ot & 1) * 128 + wo;
        const float* bp = (typ == 0) ? bias0 : (typ == 1) ? bias1 : bias2;
        const float sc = (typ == 0) ? qscale : 1.f;
        short* outp = (short*)((typ == 0) ? out0 : (typ == 1) ? out1 : out2);
        if (typ < 2) {
#pragma unroll
            for (int i = 0; i < 4; ++i) {
                const int ch0 = chbase + 16 * i + quad * 4;
                const int head = ch0 >> 5, d0 = ch0 & 31;
                float bias[4];
#pragma unroll
                for (int r = 0; r < 4; ++r) bias[r] = bp[ch0 + r];
#pragma unroll
                for (int j = 0; j < 4; ++j) {
                    const int l = lt * 128 + wl + 16 * j + c;
                    short4 sv;
                    sv.x = f2bf((acc[i][j][0] + bias[0]) * sc);
                    sv.y = f2bf((acc[i][j][1] + bias[1]) * sc);
                    sv.z = f2bf((acc[i][j][2] + bias[2]) * sc);
                    sv.w = f2bf((acc[i][j][3] + bias[3]) * sc);
                    *(short4*)&outp[(((size_t)b * NH_ + head) * L_ + l) * 32 + d0] = sv;
                }
            }
        } else {
#pragma unroll
            for (int i = 0; i < 4; ++i)
#pragma unroll
                for (int r = 0; r < 4; ++r) {
                    const int ch = chbase + 16 * i + quad * 4 + r;
                    const float bias = bp[ch];
#pragma unroll
                    for (int j = 0; j < 4; ++j)
                        outp[((size_t)b * C_ + ch) * L_ + lt * 128 + wl + 16 * j + c] =
                            f2bf(acc[i][j][r] + bias);
                }
        }
    } else {
        float* outp = (float*)out0;
#pragma unroll
        for (int i = 0; i < 4; ++i)
#pragma unroll
            for (int r = 0; r < 4; ++r) {
                const int ch = ot * 128 + wo + 16 * i + quad * 4 + r;
                const float bias = bias0[ch];
#pragma unroll
                for (int j = 0; j < 4; ++j)
                    outp[((size_t)b * C_ + ch) * L_ + lt * 128 + wl + 16 * j + c] =
                        acc[i][j][r] + bias;
            }
    }
}

// ---------------------------------------------------------------------------
// MFMA flash attention (R8 structure): 64-key tiles, double-buffered shared
// LDS K/V staging (8 KB + 8 KB), one barrier per tile, ~35 KB LDS ->
// 4 blocks/CU resident; per-wave private P^T round-trip.
// ---------------------------------------------------------------------------
__global__ __launch_bounds__(256, 4) void attn_kernel(
    const short* __restrict__ qt,   // [b][h][l][d] bf16 (scale*log2e folded)
    const short* __restrict__ kt,   // [b][h][l][d] bf16
    const short* __restrict__ vb,   // [b][c][l]    bf16
    short* __restrict__ athi)       // [b][l][c]    bf16
{
    const int flat = blockIdx.x;
    const int g = ((flat >> 6) << 3) | (flat & 7);  // (b,h) group
    const int chunk = (flat >> 3) & 7;
    const int b = g >> 3, h = g & 7;
    const int t = threadIdx.x;
    const int wv = t >> 6, lane = t & 63;
    const int quad = lane >> 4, c = lane & 15;
    const int lq0 = chunk * 128 + wv * 32;          // wave's 32 queries

    __shared__ __align__(16) short sK[2][64 * 32];      // [key][d], 64B rows
    __shared__ __align__(16) short sV[2][2][32 * 32];   // [kc][ch][key32], 64B rows
    __shared__ __align__(16) short sPT[4][2][16][72];   // per-wave P^T

    const size_t bh = (size_t)b * NH_ + h;
    const short* qbase = qt + (bh * L_) * 32;
    const short* kbase = kt + (bh * L_) * 32;
    const size_t vrow = (size_t)b * C_ + h * DH_;

    short8v qfrag[2];
#pragma unroll
    for (int qf = 0; qf < 2; ++qf)
        qfrag[qf] = *(const short8v*)(qbase + (size_t)(lq0 + qf * 16 + c) * 32 + quad * 8);

    float lp4[2][4];
#pragma unroll
    for (int qf = 0; qf < 2; ++qf)
#pragma unroll
        for (int r = 0; r < 4; ++r) lp4[qf][r] = 0.f;
    float4v o_acc[2][2];
#pragma unroll
    for (int qf = 0; qf < 2; ++qf) { o_acc[qf][0] = (float4v)0.f; o_acc[qf][1] = (float4v)0.f; }

    // cooperative staging: K rows key=t>>2 (d-seg t&3), V rows ch=(t>>2)&31
    // (kc=t>>7, key-seg t&3); LDS dest = tid*16B (lane-contiguous per wave)
    auto stage = [&](int m0, int buf) {
        gld16(kbase + (size_t)(m0 + (t >> 2)) * 32 + (t & 3) * 8, &sK[buf][t * 8]);
        gld16(vb + (vrow + ((t >> 2) & 31)) * L_ + m0 + (t >> 7) * 32 + (t & 3) * 8,
              (short*)sV[buf] + t * 8);
    };

    stage(0, 0);

    for (int i = 0; i < 16; ++i) {
        __syncthreads();                 // staging of tile i visible; buf (i+1)&1 free
        if (i < 15) stage((i + 1) * 64, (i + 1) & 1);
        const int buf = i & 1;

        short8v kf[4], vf[2][2];
#pragma unroll
        for (int kb = 0; kb < 4; ++kb)
            kf[kb] = *(const short8v*)&sK[buf][(kb * 16 + c) * 32 + quad * 8];
#pragma unroll
        for (int kc = 0; kc < 2; ++kc)
#pragma unroll
            for (int nb2 = 0; nb2 < 2; ++nb2)
                vf[kc][nb2] = *(const short8v*)&sV[buf][kc][(nb2 * 16 + c) * 32 + quad * 8];

        // S^T = K Q^T
        float4v st[2][4];
#pragma unroll
        for (int qf = 0; qf < 2; ++qf)
#pragma unroll
            for (int kb = 0; kb < 4; ++kb)
                st[qf][kb] = __builtin_amdgcn_mfma_f32_16x16x32_bf16(kf[kb], qfrag[qf], (float4v)0.f, 0, 0, 0);

        // p = exp2(s); 4 independent denom partials per qf; P^T -> LDS
#pragma unroll
        for (int qf = 0; qf < 2; ++qf)
#pragma unroll
            for (int kb = 0; kb < 4; ++kb) {
                float p[4];
#pragma unroll
                for (int r = 0; r < 4; ++r) {
                    p[r] = __builtin_amdgcn_exp2f(st[qf][kb][r]);
                    lp4[qf][r] += p[r];
                }
                uint2 w;
                w.x = pkrn(p[0], p[1]);
                w.y = pkrn(p[2], p[3]);
                *(uint2*)&sPT[wv][qf][c][kb * 16 + quad * 4] = w;
            }

        // O += V P^T
#pragma unroll
        for (int qf = 0; qf < 2; ++qf)
#pragma unroll
            for (int kc = 0; kc < 2; ++kc) {
                const short8v pf = *(const short8v*)&sPT[wv][qf][c][kc * 32 + quad * 8];
#pragma unroll
                for (int nb2 = 0; nb2 < 2; ++nb2)
                    o_acc[qf][nb2] = __builtin_amdgcn_mfma_f32_16x16x32_bf16(vf[kc][nb2], pf, o_acc[qf][nb2], 0, 0, 0);
            }
    }

#pragma unroll
    for (int qf = 0; qf < 2; ++qf) {
        float l = (lp4[qf][0] + lp4[qf][1]) + (lp4[qf][2] + lp4[qf][3]);
        l += __shfl_xor(l, 16);
        l += __shfl_xor(l, 32);
        const float inv = 1.f / l;
        // At[b][l][c]: l = lq0 + qf*16 + c, ch = h*32 + nb2*16 + quad*4 + r
#pragma unroll
        for (int nb2 = 0; nb2 < 2; ++nb2) {
            short4 sv;
            sv.x = f2bf(o_acc[qf][nb2][0] * inv);
            sv.y = f2bf(o_acc[qf][nb2][1] * inv);
            sv.z = f2bf(o_acc[qf][nb2][2] * inv);
            sv.w = f2bf(o_acc[qf][nb2][3] * inv);
            *(short4*)&athi[((size_t)b * L_ + lq0 + qf * 16 + c) * C_ + h * DH_ + nb2 * 16 + quad * 4] = sv;
        }
    }
}

}  // namespace

extern "C" void kernel_launch(void* const* d_in, const int* in_sizes, int n_in,
                              void* d_out, int out_size, void* d_ws, size_t ws_size,
                              hipStream_t stream) {
    const float* x   = (const float*)d_in[0];
    const float* w_q = (const float*)d_in[1];
    const float* b_q = (const float*)d_in[2];
    const float* w_k = (const float*)d_in[3];
    const float* b_k = (const float*)d_in[4];
    const float* w_v = (const float*)d_in[5];
    const float* b_v = (const float*)d_in[6];
    const float* w_o = (const float*)d_in[7];
    const float* b_o = (const float*)d_in[8];
    float* out = (float*)d_out;

    const size_t NT = (size_t)B_ * L_ * C_;   // 4,194,304
    short* xthi = (short*)d_ws;
    short* WA   = xthi + NT;                  // 768*512
    short* WoA  = WA + 768 * 512;             // 256*512
    short* qt   = WoA + 256 * 512;
    short* kt   = qt + NT;
    short* vb   = kt + NT;
    short* athi = vb + NT;

    const float scale_q = 0.17677669529663687f * 1.4426950408889634f; // 1/sqrt(32)*log2(e)

    xpose_kernel<<<dim3(L_ / 64, C_ / 64, B_), 256, 0, stream>>>(x, xthi);
    stackw_kernel<<<dim3(1024), 256, 0, stream>>>(w_q, w_k, w_v, w_o, WA, WoA);
    gemm_kernel<512, 0><<<dim3(L_ / 128, 6, B_), 256, 0, stream>>>(
        WA, xthi, b_q, b_k, b_v, scale_q, qt, kt, vb);
    attn_kernel<<<dim3(1024), 256, 0, stream>>>(qt, kt, vb, athi);
    gemm_kernel<512, 1><<<dim3(L_ / 128, 2, B_), 256, 0, stream>>>(
        WoA, athi, b_o, nullptr, nullptr, 1.f, out, nullptr, nullptr);
}